// Round 6
// baseline (845.096 us; speedup 1.0000x reference)
//
#include <hip/hip_runtime.h>

#define N_NODES_C 100000
#define N_GRAPHS_C 128

typedef __attribute__((ext_vector_type(8))) __bf16 bf16x8;
typedef __attribute__((ext_vector_type(4))) float f32x4;

__device__ __forceinline__ f32x4 mfma16(bf16x8 a, bf16x8 b, f32x4 c) {
    return __builtin_amdgcn_mfma_f32_16x16x32_bf16(a, b, c, 0, 0, 0);
}

// ---------------- CSR build ----------------
__global__ void hist_kernel(const int* __restrict__ ei, int E, int* __restrict__ deg) {
    int i = blockIdx.x * blockDim.x + threadIdx.x;
    if (i < E) atomicAdd(&deg[ei[E + i]], 1);   // dst row of edge_index
}

__global__ void scan1_kernel(const int* __restrict__ deg, int N,
                             int* __restrict__ tmp, int* __restrict__ bsum) {
    __shared__ int sh[512];
    int t = threadIdx.x;
    int i = blockIdx.x * 512 + t;
    int v = (i < N) ? deg[i] : 0;
    sh[t] = v;
    __syncthreads();
    for (int off = 1; off < 512; off <<= 1) {
        int add = (t >= off) ? sh[t - off] : 0;
        __syncthreads();
        sh[t] += add;
        __syncthreads();
    }
    if (i < N) tmp[i] = sh[t] - v;
    if (t == 511) bsum[blockIdx.x] = sh[511];
}

__global__ void scan2_kernel(int* bsum, int nb) {
    if (threadIdx.x == 0 && blockIdx.x == 0) {
        int run = 0;
        for (int j = 0; j < nb; ++j) { int v = bsum[j]; bsum[j] = run; run += v; }
    }
}

__global__ void scan3_kernel(const int* __restrict__ tmp, const int* __restrict__ bsum,
                             int N, int* __restrict__ rowp, int* __restrict__ rowpm) {
    int i = blockIdx.x * 512 + threadIdx.x;
    if (i < N) {
        int v = tmp[i] + bsum[blockIdx.x];
        rowp[i] = v;
        rowpm[i] = v;          // mutable copy consumed by fill as cursor
    }
}

__global__ void fill_kernel(const int* __restrict__ ei, int E,
                            int* __restrict__ rowpm, int* __restrict__ csr) {
    int i = blockIdx.x * blockDim.x + threadIdx.x;
    if (i < E) {
        int d = ei[E + i];
        int pos = atomicAdd(&rowpm[d], 1);
        __builtin_nontemporal_store(ei[i], &csr[pos]);   // src row; no-allocate hint
    }
}

// ---------------- neighbor aggregation (float4 gather, multi-edge per wave) ------
// FIN==128: 2 edges per wave-instr (32 lanes x float4 each); FIN==64: 4 edges.
template <int FIN>
__global__ __launch_bounds__(256) void agg_kernel(const float* __restrict__ xin,
                                                  const int* __restrict__ rowp,
                                                  const int* __restrict__ degv,
                                                  const int* __restrict__ csrc,
                                                  float* __restrict__ aggout, int nNodes) {
    int wave = blockIdx.x * 4 + (threadIdx.x >> 6);
    int lane = threadIdx.x & 63;
    if (wave >= nNodes) return;
    int start = rowp[wave];
    int deg = degv[wave];
    const float4* x4 = (const float4*)xin;
    constexpr int EPW = (FIN == 128) ? 2 : 4;       // edges per wave-iteration
    constexpr int RS = FIN / 4;                      // float4s per row (32 or 16)
    const int grp = lane / RS;                       // which edge in the group
    const int f4 = lane & (RS - 1);                  // float4 index within row

    float4 acc[8];
#pragma unroll
    for (int q = 0; q < 8; ++q) acc[q] = make_float4(0.f, 0.f, 0.f, 0.f);

    for (int base = 0; base < deg; base += 64) {
        int cnt = min(64, deg - base);
        int sid = (lane < cnt) ? csrc[start + base + lane] : 0;
        int j = 0;
        for (; j + 8 * EPW <= cnt; j += 8 * EPW) {   // 8*EPW edges in flight
            int n[8];
#pragma unroll
            for (int q = 0; q < 8; ++q) n[q] = __shfl(sid, j + q * EPW + grp);
            float4 v[8];
#pragma unroll
            for (int q = 0; q < 8; ++q) v[q] = x4[(size_t)n[q] * RS + f4];
#pragma unroll
            for (int q = 0; q < 8; ++q) {
                acc[q].x += v[q].x; acc[q].y += v[q].y;
                acc[q].z += v[q].z; acc[q].w += v[q].w;
            }
        }
        for (; j + EPW <= cnt; j += EPW) {
            int n0 = __shfl(sid, j + grp);
            float4 v = x4[(size_t)n0 * RS + f4];
            acc[0].x += v.x; acc[0].y += v.y; acc[0].z += v.z; acc[0].w += v.w;
        }
        for (; j < cnt; ++j) {                       // remainder: group 0 only
            int n0 = __shfl(sid, j);
            if (grp == 0) {
                float4 v = x4[(size_t)n0 * RS + f4];
                acc[0].x += v.x; acc[0].y += v.y; acc[0].z += v.z; acc[0].w += v.w;
            }
        }
    }
    float4 tot;
    tot.x = ((acc[0].x+acc[1].x)+(acc[2].x+acc[3].x)) + ((acc[4].x+acc[5].x)+(acc[6].x+acc[7].x));
    tot.y = ((acc[0].y+acc[1].y)+(acc[2].y+acc[3].y)) + ((acc[4].y+acc[5].y)+(acc[6].y+acc[7].y));
    tot.z = ((acc[0].z+acc[1].z)+(acc[2].z+acc[3].z)) + ((acc[4].z+acc[5].z)+(acc[6].z+acc[7].z));
    tot.w = ((acc[0].w+acc[1].w)+(acc[2].w+acc[3].w)) + ((acc[4].w+acc[5].w)+(acc[6].w+acc[7].w));
    // combine edge-groups: lanes with equal f4 differ by multiples of RS
    if (FIN == 64) {
        tot.x += __shfl_xor(tot.x, 16); tot.y += __shfl_xor(tot.y, 16);
        tot.z += __shfl_xor(tot.z, 16); tot.w += __shfl_xor(tot.w, 16);
    }
    tot.x += __shfl_xor(tot.x, 32); tot.y += __shfl_xor(tot.y, 32);
    tot.z += __shfl_xor(tot.z, 32); tot.w += __shfl_xor(tot.w, 32);
    if (lane < RS)
        ((float4*)aggout)[(size_t)wave * RS + lane] = tot;
}

// ---------------- weight prep: split fp32 W -> bf16 hi/lo, pre-swizzled LDS image ----
__global__ void wprep_kernel(const float* __restrict__ Wrel, const float* __restrict__ Wroot,
                             int KH, unsigned* __restrict__ img) {
    int cid = blockIdx.x;          // chunk
    int col = threadIdx.x;         // 0..127 (output channel)
    int key = (col >> 1) & 3;
    unsigned hiw[16], low[16];
#pragma unroll 4
    for (int p = 0; p < 16; ++p) {
        int k0 = cid * 32 + p * 2;
        float v0 = (k0 < KH) ? Wrel[col * KH + k0] : Wroot[col * KH + k0 - KH];
        float v1 = (k0 + 1 < KH) ? Wrel[col * KH + k0 + 1] : Wroot[col * KH + k0 + 1 - KH];
        unsigned u0 = __float_as_uint(v0), u1 = __float_as_uint(v1);
        unsigned h0 = u0 & 0xFFFF0000u, h1 = u1 & 0xFFFF0000u;
        float l0 = v0 - __uint_as_float(h0), l1 = v1 - __uint_as_float(h1);
        unsigned lb0 = __float_as_uint(l0) & 0xFFFF0000u;
        unsigned lb1 = __float_as_uint(l1) & 0xFFFF0000u;
        hiw[p] = (h0 >> 16) | h1;
        low[p] = (lb0 >> 16) | lb1;
    }
    unsigned* cb = img + (size_t)cid * 4096;
#pragma unroll 4
    for (int p = 0; p < 16; ++p) {
        int s = p >> 2, w = p & 3;
        int sp = s ^ key;
        cb[col * 16 + sp * 4 + w] = hiw[p];
        cb[2048 + col * 16 + sp * 4 + w] = low[p];
    }
}

// ---------------- fused dual-GEMM transform via split-bf16 MFMA ----------------
template <int KTOT, bool RELU>
__global__ __launch_bounds__(256, 2) void xform_kernel(
    const float* __restrict__ agg, const float* __restrict__ xin,
    const unsigned* __restrict__ wimg, const float* __restrict__ bias,
    float* __restrict__ hout, int nNodes)
{
    constexpr int KH = KTOT / 2;
    constexpr int NC = KTOT / 32;
    __shared__ unsigned sA[2][4096];   // [hi 2048 | lo 2048] uints; row stride 16 uints
    __shared__ unsigned sW[2][4096];
    const int t = threadIdx.x;
    const int nb0 = blockIdx.x * 128;

    const int srow = t >> 1;
    const int skh = t & 1;
    const int skey = (srow >> 1) & 3;
    const int gn = nb0 + srow;
    const bool gvalid = gn < nNodes;
    const size_t arow = (size_t)gn * KH;

    float4 va[4]; uint4 vw[4];
    auto loadChunk = [&](int cix) {
        int kc = cix * 32 + skh * 16;
        const float* srcA = (kc < KH) ? agg : xin;
        int kof = (kc < KH) ? kc : kc - KH;
        if (gvalid) {
#pragma unroll
            for (int q = 0; q < 4; ++q)
                va[q] = *(const float4*)&srcA[arow + kof + q * 4];
        } else {
#pragma unroll
            for (int q = 0; q < 4; ++q) va[q] = make_float4(0.f, 0.f, 0.f, 0.f);
        }
        const uint4* wsrc = (const uint4*)(wimg + (size_t)cix * 4096) + t * 4;
#pragma unroll
        for (int q = 0; q < 4; ++q) vw[q] = wsrc[q];
    };
    auto writeChunk = [&](int buf) {
        uint4* wd = (uint4*)&sW[buf][t * 16];
#pragma unroll
        for (int q = 0; q < 4; ++q) wd[q] = vw[q];
        unsigned hiw[8], low[8];
#pragma unroll
        for (int q = 0; q < 4; ++q) {
            float vv[4] = {va[q].x, va[q].y, va[q].z, va[q].w};
#pragma unroll
            for (int h = 0; h < 2; ++h) {
                unsigned u0 = __float_as_uint(vv[h * 2]), u1 = __float_as_uint(vv[h * 2 + 1]);
                unsigned h0 = u0 & 0xFFFF0000u, h1 = u1 & 0xFFFF0000u;
                float l0 = vv[h * 2] - __uint_as_float(h0);
                float l1 = vv[h * 2 + 1] - __uint_as_float(h1);
                unsigned lb0 = __float_as_uint(l0) & 0xFFFF0000u;
                unsigned lb1 = __float_as_uint(l1) & 0xFFFF0000u;
                hiw[q * 2 + h] = (h0 >> 16) | h1;
                low[q * 2 + h] = (lb0 >> 16) | lb1;
            }
        }
        int s0 = (skh * 2) ^ skey, s1 = (skh * 2 + 1) ^ skey;
        unsigned* abH = &sA[buf][srow * 16];
        unsigned* abL = &sA[buf][2048 + srow * 16];
        *(uint4*)&abH[s0 * 4] = make_uint4(hiw[0], hiw[1], hiw[2], hiw[3]);
        *(uint4*)&abH[s1 * 4] = make_uint4(hiw[4], hiw[5], hiw[6], hiw[7]);
        *(uint4*)&abL[s0 * 4] = make_uint4(low[0], low[1], low[2], low[3]);
        *(uint4*)&abL[s1 * 4] = make_uint4(low[4], low[5], low[6], low[7]);
    };

    const int lane = t & 63, wv = t >> 6;
    const int r15 = lane & 15, hi4 = lane >> 4;
    const int ckey = (r15 >> 1) & 3;
    const int cslot = (hi4 ^ ckey) * 4;
    const int arow0 = (wv * 32 + r15) * 16;
    const int arow1 = arow0 + 256;

    f32x4 acc[2][8];
#pragma unroll
    for (int g = 0; g < 2; ++g)
#pragma unroll
        for (int j = 0; j < 8; ++j) acc[g][j] = (f32x4){0.f, 0.f, 0.f, 0.f};

    float bj[8];
#pragma unroll
    for (int j = 0; j < 8; ++j) bj[j] = bias[j * 16 + r15];

    loadChunk(0);
    writeChunk(0);
    if (NC > 1) loadChunk(1);
    __syncthreads();

#pragma unroll 1
    for (int cix = 0; cix < NC; ++cix) {
        const int cur = cix & 1;
        if (cix + 1 < NC) {
            writeChunk(cur ^ 1);
            if (cix + 2 < NC) loadChunk(cix + 2);
        }
        const unsigned* A = sA[cur];
        const unsigned* W = sW[cur];
        bf16x8 ah0 = *(const bf16x8*)&A[arow0 + cslot];
        bf16x8 ah1 = *(const bf16x8*)&A[arow1 + cslot];
        bf16x8 al0 = *(const bf16x8*)&A[2048 + arow0 + cslot];
        bf16x8 al1 = *(const bf16x8*)&A[2048 + arow1 + cslot];
#pragma unroll
        for (int j = 0; j < 8; ++j) {
            int cb = (j * 16 + r15) * 16;
            bf16x8 bh = *(const bf16x8*)&W[cb + cslot];
            bf16x8 bl = *(const bf16x8*)&W[2048 + cb + cslot];
            acc[0][j] = mfma16(ah0, bh, acc[0][j]);
            acc[1][j] = mfma16(ah1, bh, acc[1][j]);
            acc[0][j] = mfma16(ah0, bl, acc[0][j]);
            acc[1][j] = mfma16(ah1, bl, acc[1][j]);
            acc[0][j] = mfma16(al0, bh, acc[0][j]);
            acc[1][j] = mfma16(al1, bh, acc[1][j]);
        }
        __syncthreads();
    }

#pragma unroll
    for (int g2 = 0; g2 < 2; ++g2) {
#pragma unroll
        for (int r = 0; r < 4; ++r) {
            int node = nb0 + wv * 32 + g2 * 16 + hi4 * 4 + r;
            if (node >= nNodes) continue;
            float* orow = &hout[(size_t)node * 128];
#pragma unroll
            for (int j = 0; j < 8; ++j) {
                float v = acc[g2][j][r] + bj[j];
                if (RELU) v = fmaxf(v, 0.f);
                orow[j * 16 + r15] = v;
            }
        }
    }
}

// ---------------- pooling (batch is SORTED: geometry, no atomics) ----------------
__global__ void bounds_kernel(const int* __restrict__ batch, int N, int* __restrict__ gstart) {
    int g = blockIdx.x * blockDim.x + threadIdx.x;
    if (g > N_GRAPHS_C) return;
    int lo = 0, hi = N;
    while (lo < hi) {
        int mid = (lo + hi) >> 1;
        if (batch[mid] < g) lo = mid + 1; else hi = mid;
    }
    gstart[g] = lo;
}

// one block per graph; 256 threads = 8 node-subsets x 32 float4-features
__global__ __launch_bounds__(256) void pool2_kernel(const float* __restrict__ h,
                                                    const int* __restrict__ gstart,
                                                    float* __restrict__ pooled) {
    int g = blockIdx.x;
    int f4 = threadIdx.x & 31;
    int sub = threadIdx.x >> 5;
    int s = gstart[g], e = gstart[g + 1];
    const float4* h4 = (const float4*)h;
    float4 acc = make_float4(0.f, 0.f, 0.f, 0.f);
    for (int n = s + sub; n < e; n += 8) {
        float4 v = h4[(size_t)n * 32 + f4];
        acc.x += v.x; acc.y += v.y; acc.z += v.z; acc.w += v.w;
    }
    __shared__ float4 sh[8][33];
    sh[sub][f4] = acc;
    __syncthreads();
    if (sub == 0) {
        float4 tot = acc;
#pragma unroll
        for (int q = 1; q < 8; ++q) {
            float4 v = sh[q][f4];
            tot.x += v.x; tot.y += v.y; tot.z += v.z; tot.w += v.w;
        }
        float inv = 1.0f / fmaxf((float)(e - s), 1.0f);
        tot.x *= inv; tot.y *= inv; tot.z *= inv; tot.w *= inv;
        ((float4*)pooled)[g * 32 + f4] = tot;
    }
}

__global__ void final_kernel(const float* __restrict__ pooled,
                             const float* __restrict__ Wlin, const float* __restrict__ blin,
                             float* __restrict__ out) {
    int idx = blockIdx.x * blockDim.x + threadIdx.x;   // 2048 = 128 x 16
    int g = idx >> 4, c = idx & 15;
    float s = 0.f;
    for (int k = 0; k < 128; ++k) s += pooled[g * 128 + k] * Wlin[c * 128 + k];
    out[idx] = s + blin[c];
}

// ---------------- launch ----------------
extern "C" void kernel_launch(void* const* d_in, const int* in_sizes, int n_in,
                              void* d_out, int out_size, void* d_ws, size_t ws_size,
                              hipStream_t stream) {
    const float* x      = (const float*)d_in[0];
    const int*   ei     = (const int*)d_in[1];
    const int*   batch  = (const int*)d_in[2];
    const float* W1_rel = (const float*)d_in[3];
    const float* b1     = (const float*)d_in[4];
    const float* W1_root= (const float*)d_in[5];
    const float* W2_rel = (const float*)d_in[6];
    const float* b2     = (const float*)d_in[7];
    const float* W2_root= (const float*)d_in[8];
    const float* W3_rel = (const float*)d_in[9];
    const float* b3     = (const float*)d_in[10];
    const float* W3_root= (const float*)d_in[11];
    const float* W_lin  = (const float*)d_in[12];
    const float* b_lin  = (const float*)d_in[13];
    float* out = (float*)d_out;

    const int N = in_sizes[2];          // 100000
    const int E = in_sizes[1] / 2;      // 1600000
    const int nb = (N + 511) / 512;

    char* base = (char*)d_ws;
    size_t off = 0;
    auto carve = [&](size_t bytes) -> void* {
        void* p = base + off;
        off = (off + bytes + 255) & ~(size_t)255;
        return p;
    };
    int*      deg    = (int*)carve((size_t)N * 4);
    int*      tmp    = (int*)carve((size_t)N * 4);
    int*      bsum   = (int*)carve(1024);
    int*      rowp   = (int*)carve((size_t)(N + 1) * 4);
    int*      rowpm  = (int*)carve((size_t)N * 4);
    int*      csr    = (int*)carve((size_t)E * 4);
    float*    aggbuf = (float*)carve((size_t)N * 128 * 4);
    float*    hA     = (float*)carve((size_t)N * 128 * 4);
    float*    hB     = (float*)carve((size_t)N * 128 * 4);
    float*    pooled = (float*)carve((size_t)N_GRAPHS_C * 128 * 4);
    int*      gstart = (int*)carve((size_t)(N_GRAPHS_C + 1) * 4);
    unsigned* wimg1  = (unsigned*)carve((size_t)4 * 4096 * 4);   // 64 KB
    unsigned* wimg2  = (unsigned*)carve((size_t)8 * 4096 * 4);   // 128 KB
    unsigned* wimg3  = (unsigned*)carve((size_t)8 * 4096 * 4);   // 128 KB
    (void)ws_size;

    hipMemsetAsync(deg, 0, (size_t)N * 4, stream);

    // weight prep (tiny)
    wprep_kernel<<<4, 128, 0, stream>>>(W1_rel, W1_root, 64, wimg1);
    wprep_kernel<<<8, 128, 0, stream>>>(W2_rel, W2_root, 128, wimg2);
    wprep_kernel<<<8, 128, 0, stream>>>(W3_rel, W3_root, 128, wimg3);

    // CSR build
    hist_kernel<<<(E + 255) / 256, 256, 0, stream>>>(ei, E, deg);
    scan1_kernel<<<nb, 512, 0, stream>>>(deg, N, tmp, bsum);
    scan2_kernel<<<1, 64, 0, stream>>>(bsum, nb);
    scan3_kernel<<<nb, 512, 0, stream>>>(tmp, bsum, N, rowp, rowpm);
    fill_kernel<<<(E + 255) / 256, 256, 0, stream>>>(ei, E, rowpm, csr);

    // graph boundaries (batch sorted)
    bounds_kernel<<<1, 192, 0, stream>>>(batch, N, gstart);

    const int aggGrid = (N + 3) / 4;     // 4 waves/block, wave per node
    const int xGrid = (N + 127) / 128;

    // layer 1 (K = 64+64)
    agg_kernel<64><<<aggGrid, 256, 0, stream>>>(x, rowp, deg, csr, aggbuf, N);
    xform_kernel<128, true><<<xGrid, 256, 0, stream>>>(aggbuf, x, wimg1, b1, hA, N);

    // layer 2 (K = 128+128)
    agg_kernel<128><<<aggGrid, 256, 0, stream>>>(hA, rowp, deg, csr, aggbuf, N);
    xform_kernel<256, true><<<xGrid, 256, 0, stream>>>(aggbuf, hA, wimg2, b2, hB, N);

    // layer 3 (K = 128+128, no relu)
    agg_kernel<128><<<aggGrid, 256, 0, stream>>>(hB, rowp, deg, csr, aggbuf, N);
    xform_kernel<256, false><<<xGrid, 256, 0, stream>>>(aggbuf, hB, wimg3, b3, hA, N);

    // pooling + classifier (no atomics)
    pool2_kernel<<<N_GRAPHS_C, 256, 0, stream>>>(hA, gstart, pooled);
    final_kernel<<<8, 256, 0, stream>>>(pooled, W_lin, b_lin, out);
}

// Round 7
// 789.022 us; speedup vs baseline: 1.0711x; 1.0711x over previous
//
#include <hip/hip_runtime.h>

#define N_NODES_C 100000
#define N_GRAPHS_C 128

typedef __attribute__((ext_vector_type(8))) __bf16 bf16x8;
typedef __attribute__((ext_vector_type(4))) float f32x4;

__device__ __forceinline__ f32x4 mfma16(bf16x8 a, bf16x8 b, f32x4 c) {
    return __builtin_amdgcn_mfma_f32_16x16x32_bf16(a, b, c, 0, 0, 0);
}

// ---------------- CSR build ----------------
__global__ void hist_kernel(const int* __restrict__ ei, int E, int* __restrict__ deg) {
    int i = blockIdx.x * blockDim.x + threadIdx.x;
    if (i < E) atomicAdd(&deg[ei[E + i]], 1);   // dst row of edge_index
}

__global__ void scan1_kernel(const int* __restrict__ deg, int N,
                             int* __restrict__ tmp, int* __restrict__ bsum) {
    __shared__ int sh[512];
    int t = threadIdx.x;
    int i = blockIdx.x * 512 + t;
    int v = (i < N) ? deg[i] : 0;
    sh[t] = v;
    __syncthreads();
    for (int off = 1; off < 512; off <<= 1) {
        int add = (t >= off) ? sh[t - off] : 0;
        __syncthreads();
        sh[t] += add;
        __syncthreads();
    }
    if (i < N) tmp[i] = sh[t] - v;
    if (t == 511) bsum[blockIdx.x] = sh[511];
}

__global__ void scan2_kernel(int* bsum, int nb) {
    if (threadIdx.x == 0 && blockIdx.x == 0) {
        int run = 0;
        for (int j = 0; j < nb; ++j) { int v = bsum[j]; bsum[j] = run; run += v; }
    }
}

__global__ void scan3_kernel(const int* __restrict__ tmp, const int* __restrict__ bsum,
                             int N, int* __restrict__ rowp, int* __restrict__ rowpm) {
    int i = blockIdx.x * 512 + threadIdx.x;
    if (i < N) {
        int v = tmp[i] + bsum[blockIdx.x];
        rowp[i] = v;
        rowpm[i] = v;          // mutable copy consumed by fill as cursor
    }
}

// dst-range passes: pass p touches only dst in [p*8192,(p+1)*8192) -> csr writes and
// rowpm atomics confined to an L2-resident window; ei re-reads served by L3.
#define FILL_EPT 8
__global__ void fill_kernel(const int* __restrict__ ei, int E,
                            int* __restrict__ rowpm, int* __restrict__ csr) {
    int p = blockIdx.y;
    int base = blockIdx.x * 256 * FILL_EPT + threadIdx.x;
#pragma unroll
    for (int k = 0; k < FILL_EPT; ++k) {
        int i = base + k * 256;
        if (i < E) {
            int d = ei[E + i];
            if ((d >> 13) == p) {
                int pos = atomicAdd(&rowpm[d], 1);
                csr[pos] = ei[i];                    // src row
            }
        }
    }
}

// ---------------- neighbor aggregation (float4 gather, multi-edge per wave) ------
// FIN==128: 2 edges per wave-instr (32 lanes x float4 each); FIN==64: 4 edges.
template <int FIN>
__global__ __launch_bounds__(256) void agg_kernel(const float* __restrict__ xin,
                                                  const int* __restrict__ rowp,
                                                  const int* __restrict__ degv,
                                                  const int* __restrict__ csrc,
                                                  float* __restrict__ aggout, int nNodes) {
    int wave = blockIdx.x * 4 + (threadIdx.x >> 6);
    int lane = threadIdx.x & 63;
    if (wave >= nNodes) return;
    int start = rowp[wave];
    int deg = degv[wave];
    const float4* x4 = (const float4*)xin;
    constexpr int EPW = (FIN == 128) ? 2 : 4;       // edges per wave-iteration
    constexpr int RS = FIN / 4;                      // float4s per row (32 or 16)
    const int grp = lane / RS;                       // which edge in the group
    const int f4 = lane & (RS - 1);                  // float4 index within row

    float4 acc[8];
#pragma unroll
    for (int q = 0; q < 8; ++q) acc[q] = make_float4(0.f, 0.f, 0.f, 0.f);

    for (int base = 0; base < deg; base += 64) {
        int cnt = min(64, deg - base);
        int sid = (lane < cnt) ? csrc[start + base + lane] : 0;
        int j = 0;
        for (; j + 8 * EPW <= cnt; j += 8 * EPW) {   // 8*EPW edges in flight
            int n[8];
#pragma unroll
            for (int q = 0; q < 8; ++q) n[q] = __shfl(sid, j + q * EPW + grp);
            float4 v[8];
#pragma unroll
            for (int q = 0; q < 8; ++q) v[q] = x4[(size_t)n[q] * RS + f4];
#pragma unroll
            for (int q = 0; q < 8; ++q) {
                acc[q].x += v[q].x; acc[q].y += v[q].y;
                acc[q].z += v[q].z; acc[q].w += v[q].w;
            }
        }
        for (; j + EPW <= cnt; j += EPW) {
            int n0 = __shfl(sid, j + grp);
            float4 v = x4[(size_t)n0 * RS + f4];
            acc[0].x += v.x; acc[0].y += v.y; acc[0].z += v.z; acc[0].w += v.w;
        }
        for (; j < cnt; ++j) {                       // remainder: group 0 only
            int n0 = __shfl(sid, j);
            if (grp == 0) {
                float4 v = x4[(size_t)n0 * RS + f4];
                acc[0].x += v.x; acc[0].y += v.y; acc[0].z += v.z; acc[0].w += v.w;
            }
        }
    }
    float4 tot;
    tot.x = ((acc[0].x+acc[1].x)+(acc[2].x+acc[3].x)) + ((acc[4].x+acc[5].x)+(acc[6].x+acc[7].x));
    tot.y = ((acc[0].y+acc[1].y)+(acc[2].y+acc[3].y)) + ((acc[4].y+acc[5].y)+(acc[6].y+acc[7].y));
    tot.z = ((acc[0].z+acc[1].z)+(acc[2].z+acc[3].z)) + ((acc[4].z+acc[5].z)+(acc[6].z+acc[7].z));
    tot.w = ((acc[0].w+acc[1].w)+(acc[2].w+acc[3].w)) + ((acc[4].w+acc[5].w)+(acc[6].w+acc[7].w));
    // combine edge-groups: lanes with equal f4 differ by multiples of RS
    if (FIN == 64) {
        tot.x += __shfl_xor(tot.x, 16); tot.y += __shfl_xor(tot.y, 16);
        tot.z += __shfl_xor(tot.z, 16); tot.w += __shfl_xor(tot.w, 16);
    }
    tot.x += __shfl_xor(tot.x, 32); tot.y += __shfl_xor(tot.y, 32);
    tot.z += __shfl_xor(tot.z, 32); tot.w += __shfl_xor(tot.w, 32);
    if (lane < RS)
        ((float4*)aggout)[(size_t)wave * RS + lane] = tot;
}

// ---------------- weight prep: split fp32 W -> bf16 hi/lo, pre-swizzled LDS image ----
__global__ void wprep_kernel(const float* __restrict__ Wrel, const float* __restrict__ Wroot,
                             int KH, unsigned* __restrict__ img) {
    int cid = blockIdx.x;          // chunk
    int col = threadIdx.x;         // 0..127 (output channel)
    int key = (col >> 1) & 3;
    unsigned hiw[16], low[16];
#pragma unroll 4
    for (int p = 0; p < 16; ++p) {
        int k0 = cid * 32 + p * 2;
        float v0 = (k0 < KH) ? Wrel[col * KH + k0] : Wroot[col * KH + k0 - KH];
        float v1 = (k0 + 1 < KH) ? Wrel[col * KH + k0 + 1] : Wroot[col * KH + k0 + 1 - KH];
        unsigned u0 = __float_as_uint(v0), u1 = __float_as_uint(v1);
        unsigned h0 = u0 & 0xFFFF0000u, h1 = u1 & 0xFFFF0000u;
        float l0 = v0 - __uint_as_float(h0), l1 = v1 - __uint_as_float(h1);
        unsigned lb0 = __float_as_uint(l0) & 0xFFFF0000u;
        unsigned lb1 = __float_as_uint(l1) & 0xFFFF0000u;
        hiw[p] = (h0 >> 16) | h1;
        low[p] = (lb0 >> 16) | lb1;
    }
    unsigned* cb = img + (size_t)cid * 4096;
#pragma unroll 4
    for (int p = 0; p < 16; ++p) {
        int s = p >> 2, w = p & 3;
        int sp = s ^ key;
        cb[col * 16 + sp * 4 + w] = hiw[p];
        cb[2048 + col * 16 + sp * 4 + w] = low[p];
    }
}

// ---------------- fused dual-GEMM transform via split-bf16 MFMA ----------------
template <int KTOT, bool RELU>
__global__ __launch_bounds__(256, 2) void xform_kernel(
    const float* __restrict__ agg, const float* __restrict__ xin,
    const unsigned* __restrict__ wimg, const float* __restrict__ bias,
    float* __restrict__ hout, int nNodes)
{
    constexpr int KH = KTOT / 2;
    constexpr int NC = KTOT / 32;
    __shared__ unsigned sA[2][4096];   // [hi 2048 | lo 2048] uints; row stride 16 uints
    __shared__ unsigned sW[2][4096];
    const int t = threadIdx.x;
    const int nb0 = blockIdx.x * 128;

    const int srow = t >> 1;
    const int skh = t & 1;
    const int skey = (srow >> 1) & 3;
    const int gn = nb0 + srow;
    const bool gvalid = gn < nNodes;
    const size_t arow = (size_t)gn * KH;

    float4 va[4]; uint4 vw[4];
    auto loadChunk = [&](int cix) {
        int kc = cix * 32 + skh * 16;
        const float* srcA = (kc < KH) ? agg : xin;
        int kof = (kc < KH) ? kc : kc - KH;
        if (gvalid) {
#pragma unroll
            for (int q = 0; q < 4; ++q)
                va[q] = *(const float4*)&srcA[arow + kof + q * 4];
        } else {
#pragma unroll
            for (int q = 0; q < 4; ++q) va[q] = make_float4(0.f, 0.f, 0.f, 0.f);
        }
        const uint4* wsrc = (const uint4*)(wimg + (size_t)cix * 4096) + t * 4;
#pragma unroll
        for (int q = 0; q < 4; ++q) vw[q] = wsrc[q];
    };
    auto writeChunk = [&](int buf) {
        uint4* wd = (uint4*)&sW[buf][t * 16];
#pragma unroll
        for (int q = 0; q < 4; ++q) wd[q] = vw[q];
        unsigned hiw[8], low[8];
#pragma unroll
        for (int q = 0; q < 4; ++q) {
            float vv[4] = {va[q].x, va[q].y, va[q].z, va[q].w};
#pragma unroll
            for (int h = 0; h < 2; ++h) {
                unsigned u0 = __float_as_uint(vv[h * 2]), u1 = __float_as_uint(vv[h * 2 + 1]);
                unsigned h0 = u0 & 0xFFFF0000u, h1 = u1 & 0xFFFF0000u;
                float l0 = vv[h * 2] - __uint_as_float(h0);
                float l1 = vv[h * 2 + 1] - __uint_as_float(h1);
                unsigned lb0 = __float_as_uint(l0) & 0xFFFF0000u;
                unsigned lb1 = __float_as_uint(l1) & 0xFFFF0000u;
                hiw[q * 2 + h] = (h0 >> 16) | h1;
                low[q * 2 + h] = (lb0 >> 16) | lb1;
            }
        }
        int s0 = (skh * 2) ^ skey, s1 = (skh * 2 + 1) ^ skey;
        unsigned* abH = &sA[buf][srow * 16];
        unsigned* abL = &sA[buf][2048 + srow * 16];
        *(uint4*)&abH[s0 * 4] = make_uint4(hiw[0], hiw[1], hiw[2], hiw[3]);
        *(uint4*)&abH[s1 * 4] = make_uint4(hiw[4], hiw[5], hiw[6], hiw[7]);
        *(uint4*)&abL[s0 * 4] = make_uint4(low[0], low[1], low[2], low[3]);
        *(uint4*)&abL[s1 * 4] = make_uint4(low[4], low[5], low[6], low[7]);
    };

    const int lane = t & 63, wv = t >> 6;
    const int r15 = lane & 15, hi4 = lane >> 4;
    const int ckey = (r15 >> 1) & 3;
    const int cslot = (hi4 ^ ckey) * 4;
    const int arow0 = (wv * 32 + r15) * 16;
    const int arow1 = arow0 + 256;

    f32x4 acc[2][8];
#pragma unroll
    for (int g = 0; g < 2; ++g)
#pragma unroll
        for (int j = 0; j < 8; ++j) acc[g][j] = (f32x4){0.f, 0.f, 0.f, 0.f};

    float bj[8];
#pragma unroll
    for (int j = 0; j < 8; ++j) bj[j] = bias[j * 16 + r15];

    loadChunk(0);
    writeChunk(0);
    if (NC > 1) loadChunk(1);
    __syncthreads();

#pragma unroll 1
    for (int cix = 0; cix < NC; ++cix) {
        const int cur = cix & 1;
        if (cix + 1 < NC) {
            writeChunk(cur ^ 1);
            if (cix + 2 < NC) loadChunk(cix + 2);
        }
        const unsigned* A = sA[cur];
        const unsigned* W = sW[cur];
        bf16x8 ah0 = *(const bf16x8*)&A[arow0 + cslot];
        bf16x8 ah1 = *(const bf16x8*)&A[arow1 + cslot];
        bf16x8 al0 = *(const bf16x8*)&A[2048 + arow0 + cslot];
        bf16x8 al1 = *(const bf16x8*)&A[2048 + arow1 + cslot];
#pragma unroll
        for (int j = 0; j < 8; ++j) {
            int cb = (j * 16 + r15) * 16;
            bf16x8 bh = *(const bf16x8*)&W[cb + cslot];
            bf16x8 bl = *(const bf16x8*)&W[2048 + cb + cslot];
            acc[0][j] = mfma16(ah0, bh, acc[0][j]);
            acc[1][j] = mfma16(ah1, bh, acc[1][j]);
            acc[0][j] = mfma16(ah0, bl, acc[0][j]);
            acc[1][j] = mfma16(ah1, bl, acc[1][j]);
            acc[0][j] = mfma16(al0, bh, acc[0][j]);
            acc[1][j] = mfma16(al1, bh, acc[1][j]);
        }
        __syncthreads();
    }

#pragma unroll
    for (int g2 = 0; g2 < 2; ++g2) {
#pragma unroll
        for (int r = 0; r < 4; ++r) {
            int node = nb0 + wv * 32 + g2 * 16 + hi4 * 4 + r;
            if (node >= nNodes) continue;
            float* orow = &hout[(size_t)node * 128];
#pragma unroll
            for (int j = 0; j < 8; ++j) {
                float v = acc[g2][j][r] + bj[j];
                if (RELU) v = fmaxf(v, 0.f);
                orow[j * 16 + r15] = v;
            }
        }
    }
}

// ---------------- pooling (batch is SORTED: geometry, no atomics) ----------------
__global__ void bounds_kernel(const int* __restrict__ batch, int N, int* __restrict__ gstart) {
    int g = blockIdx.x * blockDim.x + threadIdx.x;
    if (g > N_GRAPHS_C) return;
    int lo = 0, hi = N;
    while (lo < hi) {
        int mid = (lo + hi) >> 1;
        if (batch[mid] < g) lo = mid + 1; else hi = mid;
    }
    gstart[g] = lo;
}

// one block per graph; 256 threads = 8 node-subsets x 32 float4-features
__global__ __launch_bounds__(256) void pool2_kernel(const float* __restrict__ h,
                                                    const int* __restrict__ gstart,
                                                    float* __restrict__ pooled) {
    int g = blockIdx.x;
    int f4 = threadIdx.x & 31;
    int sub = threadIdx.x >> 5;
    int s = gstart[g], e = gstart[g + 1];
    const float4* h4 = (const float4*)h;
    float4 acc = make_float4(0.f, 0.f, 0.f, 0.f);
    for (int n = s + sub; n < e; n += 8) {
        float4 v = h4[(size_t)n * 32 + f4];
        acc.x += v.x; acc.y += v.y; acc.z += v.z; acc.w += v.w;
    }
    __shared__ float4 sh[8][33];
    sh[sub][f4] = acc;
    __syncthreads();
    if (sub == 0) {
        float4 tot = acc;
#pragma unroll
        for (int q = 1; q < 8; ++q) {
            float4 v = sh[q][f4];
            tot.x += v.x; tot.y += v.y; tot.z += v.z; tot.w += v.w;
        }
        float inv = 1.0f / fmaxf((float)(e - s), 1.0f);
        tot.x *= inv; tot.y *= inv; tot.z *= inv; tot.w *= inv;
        ((float4*)pooled)[g * 32 + f4] = tot;
    }
}

__global__ void final_kernel(const float* __restrict__ pooled,
                             const float* __restrict__ Wlin, const float* __restrict__ blin,
                             float* __restrict__ out) {
    int idx = blockIdx.x * blockDim.x + threadIdx.x;   // 2048 = 128 x 16
    int g = idx >> 4, c = idx & 15;
    float s = 0.f;
    for (int k = 0; k < 128; ++k) s += pooled[g * 128 + k] * Wlin[c * 128 + k];
    out[idx] = s + blin[c];
}

// ---------------- launch ----------------
extern "C" void kernel_launch(void* const* d_in, const int* in_sizes, int n_in,
                              void* d_out, int out_size, void* d_ws, size_t ws_size,
                              hipStream_t stream) {
    const float* x      = (const float*)d_in[0];
    const int*   ei     = (const int*)d_in[1];
    const int*   batch  = (const int*)d_in[2];
    const float* W1_rel = (const float*)d_in[3];
    const float* b1     = (const float*)d_in[4];
    const float* W1_root= (const float*)d_in[5];
    const float* W2_rel = (const float*)d_in[6];
    const float* b2     = (const float*)d_in[7];
    const float* W2_root= (const float*)d_in[8];
    const float* W3_rel = (const float*)d_in[9];
    const float* b3     = (const float*)d_in[10];
    const float* W3_root= (const float*)d_in[11];
    const float* W_lin  = (const float*)d_in[12];
    const float* b_lin  = (const float*)d_in[13];
    float* out = (float*)d_out;

    const int N = in_sizes[2];          // 100000
    const int E = in_sizes[1] / 2;      // 1600000
    const int nb = (N + 511) / 512;

    char* base = (char*)d_ws;
    size_t off = 0;
    auto carve = [&](size_t bytes) -> void* {
        void* p = base + off;
        off = (off + bytes + 255) & ~(size_t)255;
        return p;
    };
    int*      deg    = (int*)carve((size_t)N * 4);
    int*      tmp    = (int*)carve((size_t)N * 4);
    int*      bsum   = (int*)carve(1024);
    int*      rowp   = (int*)carve((size_t)(N + 1) * 4);
    int*      rowpm  = (int*)carve((size_t)N * 4);
    int*      csr    = (int*)carve((size_t)E * 4);
    float*    aggbuf = (float*)carve((size_t)N * 128 * 4);
    float*    hA     = (float*)carve((size_t)N * 128 * 4);
    float*    hB     = (float*)carve((size_t)N * 128 * 4);
    float*    pooled = (float*)carve((size_t)N_GRAPHS_C * 128 * 4);
    int*      gstart = (int*)carve((size_t)(N_GRAPHS_C + 1) * 4);
    unsigned* wimg1  = (unsigned*)carve((size_t)4 * 4096 * 4);   // 64 KB
    unsigned* wimg2  = (unsigned*)carve((size_t)8 * 4096 * 4);   // 128 KB
    unsigned* wimg3  = (unsigned*)carve((size_t)8 * 4096 * 4);   // 128 KB
    (void)ws_size;

    hipMemsetAsync(deg, 0, (size_t)N * 4, stream);

    // weight prep (tiny)
    wprep_kernel<<<4, 128, 0, stream>>>(W1_rel, W1_root, 64, wimg1);
    wprep_kernel<<<8, 128, 0, stream>>>(W2_rel, W2_root, 128, wimg2);
    wprep_kernel<<<8, 128, 0, stream>>>(W3_rel, W3_root, 128, wimg3);

    // CSR build
    hist_kernel<<<(E + 255) / 256, 256, 0, stream>>>(ei, E, deg);
    scan1_kernel<<<nb, 512, 0, stream>>>(deg, N, tmp, bsum);
    scan2_kernel<<<1, 64, 0, stream>>>(bsum, nb);
    scan3_kernel<<<nb, 512, 0, stream>>>(tmp, bsum, N, rowp, rowpm);
    const int npass = (N + 8191) >> 13;
    fill_kernel<<<dim3((E + 256 * FILL_EPT - 1) / (256 * FILL_EPT), npass), 256, 0, stream>>>(
        ei, E, rowpm, csr);

    // graph boundaries (batch sorted)
    bounds_kernel<<<1, 192, 0, stream>>>(batch, N, gstart);

    const int aggGrid = (N + 3) / 4;     // 4 waves/block, wave per node
    const int xGrid = (N + 127) / 128;

    // layer 1 (K = 64+64)
    agg_kernel<64><<<aggGrid, 256, 0, stream>>>(x, rowp, deg, csr, aggbuf, N);
    xform_kernel<128, true><<<xGrid, 256, 0, stream>>>(aggbuf, x, wimg1, b1, hA, N);

    // layer 2 (K = 128+128)
    agg_kernel<128><<<aggGrid, 256, 0, stream>>>(hA, rowp, deg, csr, aggbuf, N);
    xform_kernel<256, true><<<xGrid, 256, 0, stream>>>(aggbuf, hA, wimg2, b2, hB, N);

    // layer 3 (K = 128+128, no relu)
    agg_kernel<128><<<aggGrid, 256, 0, stream>>>(hB, rowp, deg, csr, aggbuf, N);
    xform_kernel<256, false><<<xGrid, 256, 0, stream>>>(aggbuf, hB, wimg3, b3, hA, N);

    // pooling + classifier (no atomics)
    pool2_kernel<<<N_GRAPHS_C, 256, 0, stream>>>(hA, gstart, pooled);
    final_kernel<<<8, 256, 0, stream>>>(pooled, W_lin, b_lin, out);
}